// Round 10
// baseline (671.878 us; speedup 1.0000x reference)
//
#include <hip/hip_runtime.h>

#define NN 4096
#define NSTEPS 100
#define TPB 512
#define NBLK 256     // 1 block per CU; 16 rows per block, K pinned in VGPRs

// Coherent (cross-XCD) 8-byte load/store: relaxed agent-scope atomics compile
// to sc-flagged global ops that bypass the non-coherent L1/L2 and hit the
// coherence point directly — no release/acquire cache-maintenance.
__device__ __forceinline__ void zstore_u64(float2* p, unsigned long long u) {
    __hip_atomic_store((unsigned long long*)p, u, __ATOMIC_RELAXED,
                       __HIP_MEMORY_SCOPE_AGENT);
}
__device__ __forceinline__ unsigned long long zload_u64(const float2* p) {
    return __hip_atomic_load((const unsigned long long*)p, __ATOMIC_RELAXED,
                             __HIP_MEMORY_SCOPE_AGENT);
}

// R10 = R5 (330us, the best verified structure) with ONE change: the next
// step's tagged loads are issued AFTER the publish, not after the dot.
//
// Why: R7/R8/R9 each cut VALU issue and each made the kernel SLOWER (474/490
// vs 330) — the step is NOT instruction-bound. It is bound by coherent-poll
// traffic: 1M 8B sc loads per polling round grid-wide. R5's early-issue
// (right after the dot, ~0.5us before anyone publishes) guarantees the first
// round reads pre-publish state -> 100% stale -> a full retry round: >=2M IC
// transactions/step, and the IC queueing from that traffic IS the step time.
// (Also explains R8/R9: faster dots -> consumers poll earlier -> MORE stale
// rounds -> slower. And R6: 2x poll population -> 2.6x slower.)
//
// Issuing post-publish reads the IC after the (lockstep) publishes land:
// ~1 fresh round instead of >=2. Weakly dominant: laggard producers are
// detected at laggard_publish+RTT under both schemes; on-time producers no
// longer cost a wasted full round of IC traffic.
//
// Everything else — f32 scalar dot, 128-float kA with per-iteration "+v" pin
// (the proven placement; do NOT "optimize" it, see R7/R8/R9 post-mortems),
// 31-shuffle butterfly, per-wave ODE, parity-double-buffered P, tag protocol
// — is byte-identical to R5.
__global__ __launch_bounds__(TPB, 2) void k_persist(
    const float* __restrict__ K, const float2* __restrict__ z0,
    float2* __restrict__ zb0, float2* __restrict__ zb1,
    float2* __restrict__ zfinal, const float* __restrict__ omega_p,
    const float* __restrict__ dt_p) {
    __shared__ float P[2][8][68];   // 68: +4 pad so q-stride hits new banks

    const int tid  = threadIdx.x;
    const int bid  = blockIdx.x;
    const int w    = tid >> 6, lane = tid & 63;   // w = column-eighth
    const int colbase = w * 512 + lane;           // col_j = colbase + j*64

    const float omega = *omega_p;
    const float dt    = *dt_p;
    const float inv2n = 1.0f / (2.0f * NN);

    // ---- K fragment: 16 rows x 8 strided cols = 128 scalars ----
    float kA[16][8];
#pragma unroll
    for (int r = 0; r < 16; ++r) {
        const float* Kr = K + (size_t)(bid * 16 + r) * NN + colbase;
#pragma unroll
        for (int j = 0; j < 8; ++j) kA[r][j] = Kr[j * 64];
    }

    // ---- persistent ODE state: wave w's lanes 0/32 hold rows 2w, 2w+1 ----
    float x = 0.f, y = 0.f;
    if ((lane & 31) == 0) {
        float2 zc = z0[bid * 16 + 2 * w + (lane >> 5)];
        x = zc.x; y = zc.y;
    }

    unsigned long long v[8];   // in-flight tagged loads for the NEXT step

    for (int s = 0; s < NSTEPS; ++s) {
        // Pin kA in registers: opaque redefinition each iteration so the
        // compiler can neither spill-and-reload nor refold the global loads.
#pragma unroll
        for (int r = 0; r < 16; ++r)
#pragma unroll
            for (int j = 0; j < 8; ++j) asm volatile("" : "+v"(kA[r][j]));

        // ---- gather this thread's 8 z elements into registers ----
        float zre[8], zim[8];
        if (s == 0) {
#pragma unroll
            for (int j = 0; j < 8; ++j) {
                float2 zc = z0[colbase + j * 64];
                zre[j] = zc.x; zim[j] = zc.y;
            }
        } else {
            // v[] was issued at the END of step s-1 (post-publish); in
            // lockstep it read post-publish state -> mostly fresh round 1.
            const float2* zsrc = (s & 1) ? zb1 : zb0;
            const unsigned tag = (unsigned)(s & 7);
            unsigned stale = 0u;
#pragma unroll
            for (int j = 0; j < 8; ++j)
                stale |= (((unsigned)v[j] & 7u) != tag) ? (1u << j) : 0u;
            while (stale) {                      // batched re-poll
                __builtin_amdgcn_s_sleep(1);
#pragma unroll
                for (int j = 0; j < 8; ++j)
                    if (stale & (1u << j))
                        v[j] = zload_u64(zsrc + colbase + j * 64);
#pragma unroll
                for (int j = 0; j < 8; ++j)
                    if ((stale & (1u << j)) && ((unsigned)v[j] & 7u) == tag)
                        stale &= ~(1u << j);
            }
#pragma unroll
            for (int j = 0; j < 8; ++j) {
                union { unsigned u; float f; } cx, cy;
                cx.u = (unsigned)v[j];
                cy.u = (unsigned)(v[j] >> 32);
                zre[j] = cx.f; zim[j] = cy.f;
            }
        }

        // ---- dots: 16 rows x 8 cols per thread, K and z in registers ----
        float sr[16], si[16];
#pragma unroll
        for (int r = 0; r < 16; ++r) { sr[r] = 0.f; si[r] = 0.f; }
#pragma unroll
        for (int j = 0; j < 8; ++j) {
#pragma unroll
            for (int r = 0; r < 16; ++r) {
                sr[r] += kA[r][j] * zre[j];
                si[r] += kA[r][j] * zim[j];
            }
        }

        // ---- distribute-and-halve butterfly: 31 shuffles/thread ----
        // acc index i: i<16 -> Re(row i); i>=16 -> Im(row i-16).
        float a32[32];
#pragma unroll
        for (int r = 0; r < 16; ++r) { a32[r] = sr[r]; a32[16 + r] = si[r]; }
        float b16[16];
#pragma unroll
        for (int m = 0; m < 16; ++m) {
            float aa = a32[2 * m], bb = a32[2 * m + 1];
            bool hi = lane & 1;
            float snd = hi ? aa : bb, kp = hi ? bb : aa;
            b16[m] = kp + __shfl_xor(snd, 1, 64);
        }
        float b8[8];
#pragma unroll
        for (int m = 0; m < 8; ++m) {
            float aa = b16[2 * m], bb = b16[2 * m + 1];
            bool hi = lane & 2;
            float snd = hi ? aa : bb, kp = hi ? bb : aa;
            b8[m] = kp + __shfl_xor(snd, 2, 64);
        }
        float b4[4];
#pragma unroll
        for (int m = 0; m < 4; ++m) {
            float aa = b8[2 * m], bb = b8[2 * m + 1];
            bool hi = lane & 4;
            float snd = hi ? aa : bb, kp = hi ? bb : aa;
            b4[m] = kp + __shfl_xor(snd, 4, 64);
        }
        float b2[2];
#pragma unroll
        for (int m = 0; m < 2; ++m) {
            float aa = b4[2 * m], bb = b4[2 * m + 1];
            bool hi = lane & 8;
            float snd = hi ? aa : bb, kp = hi ? bb : aa;
            b2[m] = kp + __shfl_xor(snd, 8, 64);
        }
        {
            float aa = b2[0], bb = b2[1];
            bool hi = lane & 16;
            float snd = hi ? aa : bb, kp = hi ? bb : aa;
            float red = kp + __shfl_xor(snd, 16, 64);
            // lane l holds acc index (l&31), summed over its 32-lane half
            P[s & 1][w][lane] = red;
        }
        __syncthreads();

        // ---- per-wave ODE: wave w owns rows 2w, 2w+1 ----
        {
            const int par = s & 1;
            const int r0 = 2 * w, r1 = 2 * w + 1;
            int q    = lane & 7;
            int half = (lane >> 3) & 1;
            int sel  = lane >> 4;                       // 0..3
            int rr   = (sel & 2) ? r1 : r0;
            int idx  = ((sel & 1) << 4) + rr;           // +16 selects Im
            float val = P[par][q][half * 32 + idx];
            val += __shfl_xor(val, 1, 64);              // sum over q
            val += __shfl_xor(val, 2, 64);
            val += __shfl_xor(val, 4, 64);
            val += __shfl_xor(val, 8, 64);              // sum the two halves
            float other = __shfl_xor(val, 16, 64);      // Im to lanes 0/32
            if ((lane & 31) == 0) {                     // lanes 0 and 32
                float u  = val;                         // Re(K z) row
                float vv = other;                       // Im(K z) row
                float A = x * x - y * y;                // Re(z^2)
                float B = 2.0f * x * y;                 // Im(z^2)
                float dzr = inv2n * (u  - (u * A + vv * B)) + omega * x;
                float dzi = inv2n * (vv - (u * B - vv * A)) + omega * y;
                float nx = x + dt * dzr;
                float ny = y + dt * dzi;
                float a2 = nx * nx + ny * ny;
                if (a2 >= 0.999f * 0.999f) {
                    float sc = 0.999f / sqrtf(a2);
                    nx *= sc; ny *= sc;
                }
                x = nx; y = ny;                         // state stays in regs
                int gr = bid * 16 + r0 + (lane >> 5);
                if (s == NSTEPS - 1) {
                    zfinal[gr] = make_float2(nx, ny);   // plain, untagged
                } else {
                    union { float f; unsigned u; } cx, cy;
                    cx.f = nx; cy.f = ny;
                    cx.u = (cx.u & ~7u) | (unsigned)((s + 1) & 7);
                    unsigned long long pk =
                        (unsigned long long)cx.u |
                        ((unsigned long long)cy.u << 32);
                    float2* zo = ((s + 1) & 1) ? zb1 : zb0;
                    zstore_u64(zo + gr, pk);            // fire-and-forget
                }
            }
        }

        // ---- POST-PUBLISH issue of the next step's tagged loads ----
        // (the one change vs R5: issued here, after the publishes, so the
        //  first polling round reads post-publish IC state -> ~1 round
        //  instead of >=2; saves a full 1M-transaction wasted round)
        if (s + 1 < NSTEPS) {
            const float2* zn = ((s + 1) & 1) ? zb1 : zb0;
#pragma unroll
            for (int j = 0; j < 8; ++j)
                v[j] = zload_u64(zn + colbase + j * 64);
        }
        // no trailing barrier — P is parity-double-buffered and the tag
        // protocol transitively orders (s+2)-writes after (s)-reads
    }
}

// ---- generic fallback: per-step launches ----
__global__ __launch_bounds__(256) void k_step_f32(
    const float* __restrict__ K, const float2* __restrict__ zin,
    float2* __restrict__ zout, const float* __restrict__ omega_p,
    const float* __restrict__ dt_p, int n) {
    const int wave = threadIdx.x >> 6;
    const int lane = threadIdx.x & 63;
    const int row  = blockIdx.x * 4 + wave;
    if (row >= n) return;
    float sr = 0.0f, si = 0.0f;
    for (int c = lane; c < n; c += 64) {
        float k = K[(size_t)row * n + c];
        float2 z = zin[c];
        sr += k * z.x;
        si += k * z.y;
    }
#pragma unroll
    for (int off = 32; off; off >>= 1) {
        sr += __shfl_down(sr, off, 64);
        si += __shfl_down(si, off, 64);
    }
    if (lane == 0) {
        float u = sr, v = si;
        float2 zc = zin[row];
        float x = zc.x, y = zc.y;
        float inv2n = 1.0f / (2.0f * n);
        float A = x * x - y * y, B = 2.0f * x * y;
        float dzr = inv2n * (u - (u * A + v * B)) + (*omega_p) * x;
        float dzi = inv2n * (v - (u * B - v * A)) + (*omega_p) * y;
        float nx = x + (*dt_p) * dzr, ny = y + (*dt_p) * dzi;
        float a2 = nx * nx + ny * ny;
        if (a2 >= 0.999f * 0.999f) { float sc = 0.999f / sqrtf(a2); nx *= sc; ny *= sc; }
        zout[row] = make_float2(nx, ny);
    }
}

extern "C" void kernel_launch(void* const* d_in, const int* in_sizes, int n_in,
                              void* d_out, int out_size, void* d_ws, size_t ws_size,
                              hipStream_t stream) {
    const float2* z0      = (const float2*)d_in[0];
    const float*  K       = (const float*)d_in[1];
    const float*  omega_p = (const float*)d_in[2];
    const float*  dt_p    = (const float*)d_in[3];
    const int n = in_sizes[0] / 2;
    float2* out = (float2*)d_out;

    const size_t need = 2 * (size_t)NN * sizeof(float2);   // two z buffers
    if (n == NN && ws_size >= need) {
        float2* zb0 = (float2*)d_ws;
        float2* zb1 = zb0 + NN;
        (void)hipMemsetAsync(d_ws, 0, need, stream);  // tag 0 != live tags 1,2
        k_persist<<<NBLK, TPB, 0, stream>>>(K, z0, zb0, zb1, out,
                                            omega_p, dt_p);
    } else {
        float2* zb0 = (float2*)d_ws;
        float2* zb1 = zb0 + n;
        const float2* cur = z0;
        for (int s = 0; s < NSTEPS; ++s) {
            float2* nxt = (s == NSTEPS - 1) ? out : ((s & 1) ? zb1 : zb0);
            k_step_f32<<<(n + 3) / 4, 256, 0, stream>>>(K, cur, nxt, omega_p, dt_p, n);
            cur = nxt;
        }
    }
}

// Round 11
// 463.123 us; speedup vs baseline: 1.4508x; 1.4508x over previous
//
#include <hip/hip_runtime.h>

#define NN 4096
#define NSTEPS 100
#define TPB 512
#define NBLK 256     // 1 block per CU; 16 rows per block, K pinned in VGPRs

typedef unsigned u32x4 __attribute__((ext_vector_type(4)));

// Coherent (cross-XCD) ops: sc-flagged global ops bypass the non-coherent
// L1/L2 and hit the coherence point directly.
__device__ __forceinline__ void zstore_u64(float2* p, unsigned long long u) {
    __hip_atomic_store((unsigned long long*)p, u, __ATOMIC_RELAXED,
                       __HIP_MEMORY_SCOPE_AGENT);
}
// 16B coherent poll load (2 elements per transaction). Each 8B element is
// fully covered by the one 16B read and publishes are single 8B stores, so
// per-element atomicity is preserved (no intra-element tearing possible).
#define ZLOAD16(dst, addr)                                          \
    asm volatile("global_load_dwordx4 %0, %1, off sc0 sc1"          \
                 : "=v"(dst) : "v"(addr) : "memory")

// R11 = R5 (330us, confirmed-best structure after R6..R10 bracketed it from
// every direction) with ONE lever: halve poll transactions.
//  - z exchange buffers use a PERMUTED layout: zp[(i&~511) | (i&63)<<3 |
//    ((i>>6)&7)] = z[i]. Thread (w,lane)'s 8 elements are then 64B
//    contiguous -> polled with 4 x global_load_dwordx4 sc0 sc1 (16B) instead
//    of 8 x 8B atomic loads: 1M -> 512K transactions per polling round
//    grid-wide. If the coherence point is request-rate-limited (the one
//    hypothesis consistent with R6 2x-population=2.6x-slower and untouched
//    by R7-R10), round service time halves.
//  - Issue points identical to R5: round A issued right after the dot
//    (hidden under butterfly+barrier+ODE), checked at next loop top,
//    batched re-poll of stale granules.
//  - Hand waitcnt: vmcnt(1) at first check (the 1 = this wave's in-flight
//    publish store, issued after the 4 loads), vmcnt(0) in retries; each
//    followed by sched_barrier(0) so the tag checks can't hoist (rule #18).
//  - kA stays 128 f32 with per-iteration "+v" pin (R7/R8/R9 all proved every
//    alternative placement worse). Butterfly/ODE/tag protocol: R5 verbatim.
__global__ __launch_bounds__(TPB, 2) void k_persist(
    const float* __restrict__ K, const float2* __restrict__ z0,
    float2* __restrict__ zb0, float2* __restrict__ zb1,
    float2* __restrict__ zfinal, const float* __restrict__ omega_p,
    const float* __restrict__ dt_p) {
    __shared__ float P[2][8][68];   // 68: +4 pad so q-stride hits new banks

    const int tid  = threadIdx.x;
    const int bid  = blockIdx.x;
    const int w    = tid >> 6, lane = tid & 63;   // w = column-eighth
    const int colbase = w * 512 + lane;           // col_j = colbase + j*64

    const float omega = *omega_p;
    const float dt    = *dt_p;
    const float inv2n = 1.0f / (2.0f * NN);

    // ---- K fragment: 16 rows x 8 strided cols = 128 scalars ----
    float kA[16][8];
#pragma unroll
    for (int r = 0; r < 16; ++r) {
        const float* Kr = K + (size_t)(bid * 16 + r) * NN + colbase;
#pragma unroll
        for (int j = 0; j < 8; ++j) kA[r][j] = Kr[j * 64];
    }

    // ---- persistent ODE state: wave w's lanes 0/32 hold rows 2w, 2w+1 ----
    float x = 0.f, y = 0.f;
    if ((lane & 31) == 0) {
        float2 zc = z0[bid * 16 + 2 * w + (lane >> 5)];
        x = zc.x; y = zc.y;
    }

    // this thread's poll base in the PERMUTED buffer: 64B contiguous
    const int zpbase = (w << 9) + (lane << 3);    // element index
    u32x4 va[4];   // in-flight tagged 16B loads for the NEXT step

    for (int s = 0; s < NSTEPS; ++s) {
        // Pin kA in registers: opaque redefinition each iteration so the
        // compiler can neither spill-and-reload nor refold the global loads.
#pragma unroll
        for (int r = 0; r < 16; ++r)
#pragma unroll
            for (int j = 0; j < 8; ++j) asm volatile("" : "+v"(kA[r][j]));

        // ---- gather this thread's 8 z elements into registers ----
        float zre[8], zim[8];
        if (s == 0) {
#pragma unroll
            for (int j = 0; j < 8; ++j) {
                float2 zc = z0[colbase + j * 64];
                zre[j] = zc.x; zim[j] = zc.y;
            }
        } else {
            // va[] was issued after last step's dot (round A, hidden under
            // butterfly+barrier+ODE). Check; re-poll stale granules batched.
            const float2* zsrc = (s & 1) ? zb1 : zb0;
            const unsigned tag = (unsigned)(s & 7);
            const float2* gb = zsrc + zpbase;
            // wait the 4 loads; allow the (later-issued) publish store to
            // stay in flight
            asm volatile("s_waitcnt vmcnt(1)" ::: "memory");
            __builtin_amdgcn_sched_barrier(0);
            unsigned stale = 0u;
#pragma unroll
            for (int g = 0; g < 4; ++g)
                if (((va[g][0] & 7u) != tag) || ((va[g][2] & 7u) != tag))
                    stale |= 1u << g;
            while (stale) {
                __builtin_amdgcn_s_sleep(1);
#pragma unroll
                for (int g = 0; g < 4; ++g)
                    if (stale & (1u << g)) ZLOAD16(va[g], gb + 2 * g);
                asm volatile("s_waitcnt vmcnt(0)" ::: "memory");
                __builtin_amdgcn_sched_barrier(0);
#pragma unroll
                for (int g = 0; g < 4; ++g)
                    if ((stale & (1u << g)) && ((va[g][0] & 7u) == tag) &&
                        ((va[g][2] & 7u) == tag))
                        stale &= ~(1u << g);
            }
#pragma unroll
            for (int g = 0; g < 4; ++g) {
                union { unsigned u; float f; } t0, t1, t2, t3;
                t0.u = va[g][0]; t1.u = va[g][1];
                t2.u = va[g][2]; t3.u = va[g][3];
                zre[2 * g]     = t0.f; zim[2 * g]     = t1.f;
                zre[2 * g + 1] = t2.f; zim[2 * g + 1] = t3.f;
            }
        }

        // ---- dots: 16 rows x 8 cols per thread, K and z in registers ----
        float sr[16], si[16];
#pragma unroll
        for (int r = 0; r < 16; ++r) { sr[r] = 0.f; si[r] = 0.f; }
#pragma unroll
        for (int j = 0; j < 8; ++j) {
#pragma unroll
            for (int r = 0; r < 16; ++r) {
                sr[r] += kA[r][j] * zre[j];
                si[r] += kA[r][j] * zim[j];
            }
        }

        // ---- EARLY-ISSUE round A for step s+1 (R5 placement: flies during
        //      butterfly + barrier + ODE; checked at next loop top) ----
        if (s + 1 < NSTEPS) {
            const float2* zn = ((s + 1) & 1) ? zb1 : zb0;
            const float2* gb = zn + zpbase;
#pragma unroll
            for (int g = 0; g < 4; ++g) ZLOAD16(va[g], gb + 2 * g);
        }

        // ---- distribute-and-halve butterfly: 31 shuffles/thread ----
        // acc index i: i<16 -> Re(row i); i>=16 -> Im(row i-16).
        float a32[32];
#pragma unroll
        for (int r = 0; r < 16; ++r) { a32[r] = sr[r]; a32[16 + r] = si[r]; }
        float b16[16];
#pragma unroll
        for (int m = 0; m < 16; ++m) {
            float aa = a32[2 * m], bb = a32[2 * m + 1];
            bool hi = lane & 1;
            float snd = hi ? aa : bb, kp = hi ? bb : aa;
            b16[m] = kp + __shfl_xor(snd, 1, 64);
        }
        float b8[8];
#pragma unroll
        for (int m = 0; m < 8; ++m) {
            float aa = b16[2 * m], bb = b16[2 * m + 1];
            bool hi = lane & 2;
            float snd = hi ? aa : bb, kp = hi ? bb : aa;
            b8[m] = kp + __shfl_xor(snd, 2, 64);
        }
        float b4[4];
#pragma unroll
        for (int m = 0; m < 4; ++m) {
            float aa = b8[2 * m], bb = b8[2 * m + 1];
            bool hi = lane & 4;
            float snd = hi ? aa : bb, kp = hi ? bb : aa;
            b4[m] = kp + __shfl_xor(snd, 4, 64);
        }
        float b2[2];
#pragma unroll
        for (int m = 0; m < 2; ++m) {
            float aa = b4[2 * m], bb = b4[2 * m + 1];
            bool hi = lane & 8;
            float snd = hi ? aa : bb, kp = hi ? bb : aa;
            b2[m] = kp + __shfl_xor(snd, 8, 64);
        }
        {
            float aa = b2[0], bb = b2[1];
            bool hi = lane & 16;
            float snd = hi ? aa : bb, kp = hi ? bb : aa;
            float red = kp + __shfl_xor(snd, 16, 64);
            // lane l holds acc index (l&31), summed over its 32-lane half
            P[s & 1][w][lane] = red;
        }
        __syncthreads();

        // ---- per-wave ODE: wave w owns rows 2w, 2w+1 ----
        {
            const int par = s & 1;
            const int r0 = 2 * w, r1 = 2 * w + 1;
            int q    = lane & 7;
            int half = (lane >> 3) & 1;
            int sel  = lane >> 4;                       // 0..3
            int rr   = (sel & 2) ? r1 : r0;
            int idx  = ((sel & 1) << 4) + rr;           // +16 selects Im
            float val = P[par][q][half * 32 + idx];
            val += __shfl_xor(val, 1, 64);              // sum over q
            val += __shfl_xor(val, 2, 64);
            val += __shfl_xor(val, 4, 64);
            val += __shfl_xor(val, 8, 64);              // sum the two halves
            float other = __shfl_xor(val, 16, 64);      // Im to lanes 0/32
            if ((lane & 31) == 0) {                     // lanes 0 and 32
                float u  = val;                         // Re(K z) row
                float vv = other;                       // Im(K z) row
                float A = x * x - y * y;                // Re(z^2)
                float B = 2.0f * x * y;                 // Im(z^2)
                float dzr = inv2n * (u  - (u * A + vv * B)) + omega * x;
                float dzi = inv2n * (vv - (u * B - vv * A)) + omega * y;
                float nx = x + dt * dzr;
                float ny = y + dt * dzi;
                float a2 = nx * nx + ny * ny;
                if (a2 >= 0.999f * 0.999f) {
                    float sc = 0.999f / sqrtf(a2);
                    nx *= sc; ny *= sc;
                }
                x = nx; y = ny;                         // state stays in regs
                int gr = bid * 16 + r0 + (lane >> 5);
                if (s == NSTEPS - 1) {
                    zfinal[gr] = make_float2(nx, ny);   // plain, untagged
                } else {
                    union { float f; unsigned u; } cx, cy;
                    cx.f = nx; cy.f = ny;
                    cx.u = (cx.u & ~7u) | (unsigned)((s + 1) & 7);
                    unsigned long long pk =
                        (unsigned long long)cx.u |
                        ((unsigned long long)cy.u << 32);
                    float2* zo = ((s + 1) & 1) ? zb1 : zb0;
                    // PERMUTED publish index: i -> (i&~511)|((i&63)<<3)|(i>>6 &7)
                    int o = gr & 511;
                    int zpidx = (gr & ~511) | ((o & 63) << 3) | (o >> 6);
                    zstore_u64(zo + zpidx, pk);         // fire-and-forget
                }
            }
        }
        // no trailing barrier — P is parity-double-buffered and the tag
        // protocol transitively orders (s+2)-writes after (s)-reads
    }
}

// ---- generic fallback: per-step launches (plain layout, unchanged) ----
__global__ __launch_bounds__(256) void k_step_f32(
    const float* __restrict__ K, const float2* __restrict__ zin,
    float2* __restrict__ zout, const float* __restrict__ omega_p,
    const float* __restrict__ dt_p, int n) {
    const int wave = threadIdx.x >> 6;
    const int lane = threadIdx.x & 63;
    const int row  = blockIdx.x * 4 + wave;
    if (row >= n) return;
    float sr = 0.0f, si = 0.0f;
    for (int c = lane; c < n; c += 64) {
        float k = K[(size_t)row * n + c];
        float2 z = zin[c];
        sr += k * z.x;
        si += k * z.y;
    }
#pragma unroll
    for (int off = 32; off; off >>= 1) {
        sr += __shfl_down(sr, off, 64);
        si += __shfl_down(si, off, 64);
    }
    if (lane == 0) {
        float u = sr, v = si;
        float2 zc = zin[row];
        float x = zc.x, y = zc.y;
        float inv2n = 1.0f / (2.0f * n);
        float A = x * x - y * y, B = 2.0f * x * y;
        float dzr = inv2n * (u - (u * A + v * B)) + (*omega_p) * x;
        float dzi = inv2n * (v - (u * B - v * A)) + (*omega_p) * y;
        float nx = x + (*dt_p) * dzr, ny = y + (*dt_p) * dzi;
        float a2 = nx * nx + ny * ny;
        if (a2 >= 0.999f * 0.999f) { float sc = 0.999f / sqrtf(a2); nx *= sc; ny *= sc; }
        zout[row] = make_float2(nx, ny);
    }
}

extern "C" void kernel_launch(void* const* d_in, const int* in_sizes, int n_in,
                              void* d_out, int out_size, void* d_ws, size_t ws_size,
                              hipStream_t stream) {
    const float2* z0      = (const float2*)d_in[0];
    const float*  K       = (const float*)d_in[1];
    const float*  omega_p = (const float*)d_in[2];
    const float*  dt_p    = (const float*)d_in[3];
    const int n = in_sizes[0] / 2;
    float2* out = (float2*)d_out;

    const size_t need = 2 * (size_t)NN * sizeof(float2);   // two z buffers
    if (n == NN && ws_size >= need) {
        float2* zb0 = (float2*)d_ws;
        float2* zb1 = zb0 + NN;
        (void)hipMemsetAsync(d_ws, 0, need, stream);  // tag 0 != live tags 1,2
        k_persist<<<NBLK, TPB, 0, stream>>>(K, z0, zb0, zb1, out,
                                            omega_p, dt_p);
    } else {
        float2* zb0 = (float2*)d_ws;
        float2* zb1 = zb0 + n;
        const float2* cur = z0;
        for (int s = 0; s < NSTEPS; ++s) {
            float2* nxt = (s == NSTEPS - 1) ? out : ((s & 1) ? zb1 : zb0);
            k_step_f32<<<(n + 3) / 4, 256, 0, stream>>>(K, cur, nxt, omega_p, dt_p, n);
            cur = nxt;
        }
    }
}